// Round 2
// baseline (631.318 us; speedup 1.0000x reference)
//
#include <hip/hip_runtime.h>

#define NMAX 8192

// ---------------- K1: stable descending rank by confidence ----------------
__global__ void k_rank(const float* __restrict__ preds, int n,
                       float* __restrict__ sboxes, int* __restrict__ sidx) {
  __shared__ float cs[NMAX];
  for (int j = threadIdx.x; j < n; j += blockDim.x)
    cs[j] = preds[j * 5 + 4];
  __syncthreads();
  int i = blockIdx.x * blockDim.x + threadIdx.x;
  if (i >= n) return;
  float ci = cs[i];
  int pos = 0;
  for (int j = 0; j < n; ++j) {
    float cj = cs[j];
    pos += (cj > ci) || (cj == ci && j < i);
  }
  // scatter box (sorted order) + original index
  sboxes[pos * 4 + 0] = preds[i * 5 + 0];
  sboxes[pos * 4 + 1] = preds[i * 5 + 1];
  sboxes[pos * 4 + 2] = preds[i * 5 + 2];
  sboxes[pos * 4 + 3] = preds[i * 5 + 3];
  sidx[pos] = i;
}

// ---------------- K2: suppression bitmask M[i][w] ----------------
// bit (lane) of M[i][w] = (col=w*64+lane) > i && IoU(i,col) > thresh
__global__ void k_mask(const float* __restrict__ sboxes, int n,
                       const float* __restrict__ thr_p,
                       unsigned long long* __restrict__ M, int nw) {
  int wx = blockIdx.x;      // column word
  int ry = blockIdx.y;      // row group
  int lane = threadIdx.x;   // 0..63

  if (wx < ry) {            // every col < every row -> all zero
    int i = ry * 64 + lane;
    if (i < n) M[(size_t)i * nw + wx] = 0ULL;
    return;
  }

  float th = *thr_p;
  int col = wx * 64 + lane;
  int colc = col < n ? col : n - 1;
  float cx1 = sboxes[colc * 4 + 0];
  float cy1 = sboxes[colc * 4 + 1];
  float cx2 = sboxes[colc * 4 + 2];
  float cy2 = sboxes[colc * 4 + 3];
  float carea = __fmul_rn(__fsub_rn(cx2, cx1), __fsub_rn(cy2, cy1));

  for (int k = 0; k < 64; ++k) {
    int i = ry * 64 + k;
    if (i >= n) break;
    float rx1 = sboxes[i * 4 + 0];
    float ry1 = sboxes[i * 4 + 1];
    float rx2 = sboxes[i * 4 + 2];
    float ry2 = sboxes[i * 4 + 3];
    float rarea = __fmul_rn(__fsub_rn(rx2, rx1), __fsub_rn(ry2, ry1));
    float ix1 = fmaxf(rx1, cx1);
    float iy1 = fmaxf(ry1, cy1);
    float ix2 = fminf(rx2, cx2);
    float iy2 = fminf(ry2, cy2);
    float iw = fmaxf(__fsub_rn(ix2, ix1), 0.0f);
    float ih = fmaxf(__fsub_rn(iy2, iy1), 0.0f);
    float inter = __fmul_rn(iw, ih);
    // reference order: (area_i + area_j - inter) + 1e-12
    float denom = __fadd_rn(__fsub_rn(__fadd_rn(rarea, carea), inter), 1e-12f);
    float iou = __fdiv_rn(inter, denom);
    bool sup = (col > i) && (col < n) && (iou > th);
    unsigned long long w = __ballot(sup);
    if (lane == 0) M[(size_t)i * nw + wx] = w;
  }
}

// ---------------- K3: sequential greedy scan (single workgroup) ----------------
__global__ void k_scan(const unsigned long long* __restrict__ M, int n, int nw,
                       int maxp, int* __restrict__ sel, int* __restrict__ cnt) {
  __shared__ unsigned long long keep[128];
  int t = threadIdx.x;  // 0..nw-1 (nw <= 128)
  keep[t] = ~0ULL;
  __syncthreads();

  int out = 0;
  for (int c = 0; c < nw; ++c) {
    if (out >= maxp) break;
    unsigned long long rem = keep[c];
    while (rem) {
      int b = __builtin_ctzll(rem);
      int i = c * 64 + b;
      if (t == 0) sel[out] = i;
      ++out;
      if (out >= maxp) break;
      // AND out row i (boxes suppressed by kept box i)
      unsigned long long r = M[(size_t)i * nw + t];
      __syncthreads();          // all threads done reading keep[c]
      keep[t] &= ~r;
      __syncthreads();          // writes visible
      unsigned long long maskLE =
          (b == 63) ? ~0ULL : ((1ULL << (b + 1)) - 1ULL);
      rem = keep[c] & ~maskLE;  // skip cleared bits; only > b remain
    }
  }
  if (t == 0) *cnt = out;
}

// ---------------- K4: gather outputs ----------------
__global__ void k_emit(const float* __restrict__ preds,
                       const int* __restrict__ sidx,
                       const int* __restrict__ sel,
                       const int* __restrict__ cnt,
                       int maxp, float* __restrict__ out) {
  int k = blockIdx.x * blockDim.x + threadIdx.x;
  if (k >= maxp) return;
  int nk = *cnt;
  if (k < nk) {
    int p = sel[k];
    int orig = sidx[p];
#pragma unroll
    for (int q = 0; q < 5; ++q) out[k * 5 + q] = preds[orig * 5 + q];
    out[(size_t)maxp * 5 + k] = (float)orig;
  } else {
#pragma unroll
    for (int q = 0; q < 5; ++q) out[k * 5 + q] = 0.0f;
    out[(size_t)maxp * 5 + k] = -1.0f;
  }
}

extern "C" void kernel_launch(void* const* d_in, const int* in_sizes, int n_in,
                              void* d_out, int out_size, void* d_ws, size_t ws_size,
                              hipStream_t stream) {
  const float* preds = (const float*)d_in[0];
  const float* thr   = (const float*)d_in[1];
  float* out = (float*)d_out;
  int n    = in_sizes[0] / 5;          // 8192
  int maxp = out_size / 6;             // 1000 (5 box cols + 1 idx col)
  int nw   = (n + 63) / 64;            // 128

  char* ws = (char*)d_ws;
  unsigned long long* M = (unsigned long long*)ws;
  size_t off = (size_t)n * nw * sizeof(unsigned long long);   // 8 MB
  float* sboxes = (float*)(ws + off);  off += (size_t)n * 4 * sizeof(float);
  int*   sidx   = (int*)(ws + off);    off += (size_t)n * sizeof(int);
  int*   sel    = (int*)(ws + off);    off += (size_t)maxp * sizeof(int);
  int*   cnt    = (int*)(ws + off);

  hipLaunchKernelGGL(k_rank, dim3((n + 255) / 256), dim3(256), 0, stream,
                     preds, n, sboxes, sidx);
  hipLaunchKernelGGL(k_mask, dim3(nw, nw), dim3(64), 0, stream,
                     sboxes, n, thr, M, nw);
  hipLaunchKernelGGL(k_scan, dim3(1), dim3(nw), 0, stream,
                     M, n, nw, maxp, sel, cnt);
  hipLaunchKernelGGL(k_emit, dim3((maxp + 255) / 256), dim3(256), 0, stream,
                     preds, sidx, sel, cnt, maxp, out);
}

// Round 3
// 299.890 us; speedup vs baseline: 2.1052x; 2.1052x over previous
//
#include <hip/hip_runtime.h>

typedef unsigned long long u64;

#define CH 256   // cols per scan chunk
#define CW 4     // 64-bit words per chunk

// ---------------- K1a: partial rank counts ----------------
// pos[i] = #{j: conf_j > conf_i  ||  (conf_j == conf_i && j < i)}  (stable desc rank)
__global__ void k_rank_part(const float* __restrict__ preds, int n, int cpb,
                            int* __restrict__ pos) {
  __shared__ float cs[1024];
  int c0 = blockIdx.y * cpb;
  int cn = min(cpb, n - c0);
  for (int j = threadIdx.x; j < cn; j += blockDim.x)
    cs[j] = preds[(c0 + j) * 5 + 4];
  __syncthreads();
  int i = blockIdx.x * blockDim.x + threadIdx.x;
  if (i >= n) return;
  float ci = preds[i * 5 + 4];
  int cnt = 0;
  for (int j = 0; j < cn; ++j) {
    float cj = cs[j];
    int jj = c0 + j;
    cnt += (cj > ci) || (cj == ci && jj < i);
  }
  atomicAdd(&pos[i], cnt);
}

// ---------------- K1b: scatter into sorted order ----------------
__global__ void k_rank_scatter(const float* __restrict__ preds,
                               const int* __restrict__ pos, int n,
                               float* __restrict__ sboxes, int* __restrict__ sidx) {
  int i = blockIdx.x * blockDim.x + threadIdx.x;
  if (i >= n) return;
  int p = pos[i];
  sboxes[p * 4 + 0] = preds[i * 5 + 0];
  sboxes[p * 4 + 1] = preds[i * 5 + 1];
  sboxes[p * 4 + 2] = preds[i * 5 + 2];
  sboxes[p * 4 + 3] = preds[i * 5 + 3];
  sidx[p] = i;
}

// ---------------- K2: suppression bitmask, transposed layout ----------------
// T[w*n + row] : bit j = IoU(row, col=w*64+j) > thresh && col > row
// Only upper triangle (w >= row/64) is written; sub-diagonal words are never
// read in a way that matters (they only AND into already-drained scan words).
__global__ void k_mask(const float* __restrict__ sboxes, int n,
                       const float* __restrict__ thr_p,
                       u64* __restrict__ T) {
  int wx = blockIdx.x;  // column word
  int ry = blockIdx.y;  // row group
  if (wx < ry) return;
  int lane = threadIdx.x;

  __shared__ float cbx1[64], cby1[64], cbx2[64], cby2[64], cbar[64];
  int col0 = wx * 64;
  int cj = col0 + lane;
  int cjc = cj < n ? cj : n - 1;
  {
    float x1 = sboxes[cjc * 4 + 0];
    float y1 = sboxes[cjc * 4 + 1];
    float x2 = sboxes[cjc * 4 + 2];
    float y2 = sboxes[cjc * 4 + 3];
    cbx1[lane] = x1; cby1[lane] = y1; cbx2[lane] = x2; cby2[lane] = y2;
    cbar[lane] = __fmul_rn(__fsub_rn(x2, x1), __fsub_rn(y2, y1));
  }
  __syncthreads();

  int row = ry * 64 + lane;
  if (row >= n) return;
  float th = *thr_p;
  float rx1 = sboxes[row * 4 + 0];
  float ry1 = sboxes[row * 4 + 1];
  float rx2 = sboxes[row * 4 + 2];
  float ry2 = sboxes[row * 4 + 3];
  float rarea = __fmul_rn(__fsub_rn(rx2, rx1), __fsub_rn(ry2, ry1));

  u64 w = 0;
#pragma unroll 8
  for (int j = 0; j < 64; ++j) {
    float ix1 = fmaxf(rx1, cbx1[j]);
    float iy1 = fmaxf(ry1, cby1[j]);
    float ix2 = fminf(rx2, cbx2[j]);
    float iy2 = fminf(ry2, cby2[j]);
    float iw = fmaxf(__fsub_rn(ix2, ix1), 0.0f);
    float ih = fmaxf(__fsub_rn(iy2, iy1), 0.0f);
    float inter = __fmul_rn(iw, ih);
    float denom = __fadd_rn(__fsub_rn(__fadd_rn(rarea, cbar[j]), inter), 1e-12f);
    float iou = __fdiv_rn(inter, denom);
    int col = col0 + j;
    bool sup = (col > row) && (col < n) && (iou > th);
    w |= ((u64)sup) << j;
  }
  T[(size_t)wx * n + row] = w;  // coalesced: consecutive lanes -> consecutive rows
}

// ---------------- K3: chunked greedy scan (1 WG, 5 waves) ----------------
// Per 256-col chunk: waves 1-4 gather OR of kept rows' column words (lazy keep
// materialization); wave 0 loads the diagonal block into registers and does the
// sequential bit-scan with shfl broadcasts. 32 latency rounds instead of ~500.
__global__ void k_scan(const u64* __restrict__ T, int n, int nw, int maxp,
                       int* __restrict__ sel, int* __restrict__ cnt) {
  __shared__ int klist[8192];
  __shared__ u64 g[CW];
  __shared__ int kcnt_s;
  __shared__ int done_s;
  int t = threadIdx.x;
  int wave = t >> 6, lane = t & 63;
  if (t == 0) { kcnt_s = 0; done_s = 0; }
  __syncthreads();

  int nch = (nw + CW - 1) / CW;
  int out = 0;   // replicated in wave 0
  int kc = 0;    // replicated in wave 0

  for (int c = 0; c < nch; ++c) {
    if (done_s) break;              // consistent: read after barrier
    int kc_all = kcnt_s;

    u64 d0[CW], d1[CW], d2[CW], d3[CW];  // wave0: rows lane, 64+lane, 128+lane, 192+lane
    if (wave == 0) {
#pragma unroll
      for (int q = 0; q < CW; ++q) {
        int w = c * CW + q;
        size_t base = (size_t)w * n;
        int r0 = c * CH + lane;
        d0[q] = (w < nw && r0       < n) ? T[base + r0]       : 0ULL;
        d1[q] = (w < nw && r0 + 64  < n) ? T[base + r0 + 64]  : 0ULL;
        d2[q] = (w < nw && r0 + 128 < n) ? T[base + r0 + 128] : 0ULL;
        d3[q] = (w < nw && r0 + 192 < n) ? T[base + r0 + 192] : 0ULL;
      }
    } else {
      int q = wave - 1;
      int w = c * CW + q;
      u64 part = 0;
      if (w < nw) {
        size_t base = (size_t)w * n;
        for (int i = lane; i < kc_all; i += 64)
          part |= T[base + klist[i]];
      }
#pragma unroll
      for (int off = 32; off; off >>= 1) part |= __shfl_down(part, off, 64);
      if (lane == 0) g[q] = part;
    }
    __syncthreads();

    if (wave == 0) {
      int base_col = c * CH;
      u64 rem[CW];
#pragma unroll
      for (int q = 0; q < CW; ++q) {
        u64 r = ~g[q];
        int wb = base_col + q * 64;
        if (wb >= n) r = 0ULL;
        else if (wb + 64 > n) r &= (1ULL << (n - wb)) - 1ULL;
        rem[q] = r;
      }
      bool stop = false;
#pragma unroll
      for (int q = 0; q < CW; ++q) {
        if (stop) break;
        while (rem[q]) {
          int b = __builtin_ctzll(rem[q]);
          int p = base_col + q * 64 + b;
          if (lane == 0) {
            klist[kc] = p;
            if (out < maxp) sel[out] = p;
          }
          ++kc; ++out;
          if (out >= maxp) { stop = true; break; }
          // broadcast suppressor row p's 4 chunk-words from the owner lane b
          u64 s0 = __shfl((q == 0) ? d0[0] : (q == 1) ? d1[0] : (q == 2) ? d2[0] : d3[0], b, 64);
          u64 s1 = __shfl((q == 0) ? d0[1] : (q == 1) ? d1[1] : (q == 2) ? d2[1] : d3[1], b, 64);
          u64 s2 = __shfl((q == 0) ? d0[2] : (q == 1) ? d1[2] : (q == 2) ? d2[2] : d3[2], b, 64);
          u64 s3 = __shfl((q == 0) ? d0[3] : (q == 1) ? d1[3] : (q == 2) ? d2[3] : d3[3], b, 64);
          rem[0] &= ~s0; rem[1] &= ~s1; rem[2] &= ~s2; rem[3] &= ~s3;
          u64 mle = (b == 63) ? ~0ULL : ((1ULL << (b + 1)) - 1ULL);
          rem[q] &= ~mle;
        }
      }
      if (lane == 0) {
        kcnt_s = kc;
        if (stop) done_s = 1;
      }
    }
    __syncthreads();
  }
  if (t == 0) *cnt = (out < maxp) ? out : maxp;
}

// ---------------- K4: gather outputs ----------------
__global__ void k_emit(const float* __restrict__ preds,
                       const int* __restrict__ sidx,
                       const int* __restrict__ sel,
                       const int* __restrict__ cnt,
                       int maxp, float* __restrict__ out) {
  int k = blockIdx.x * blockDim.x + threadIdx.x;
  if (k >= maxp) return;
  int nk = *cnt;
  if (k < nk) {
    int p = sel[k];
    int orig = sidx[p];
#pragma unroll
    for (int q = 0; q < 5; ++q) out[k * 5 + q] = preds[orig * 5 + q];
    out[(size_t)maxp * 5 + k] = (float)orig;
  } else {
#pragma unroll
    for (int q = 0; q < 5; ++q) out[k * 5 + q] = 0.0f;
    out[(size_t)maxp * 5 + k] = -1.0f;
  }
}

extern "C" void kernel_launch(void* const* d_in, const int* in_sizes, int n_in,
                              void* d_out, int out_size, void* d_ws, size_t ws_size,
                              hipStream_t stream) {
  const float* preds = (const float*)d_in[0];
  const float* thr   = (const float*)d_in[1];
  float* out = (float*)d_out;
  int n    = in_sizes[0] / 5;          // 8192
  int maxp = out_size / 6;             // 1000
  int nw   = (n + 63) / 64;            // 128

  char* ws = (char*)d_ws;
  u64* T = (u64*)ws;
  size_t off = (size_t)nw * n * sizeof(u64);                 // 8 MB
  float* sboxes = (float*)(ws + off);  off += (size_t)n * 4 * sizeof(float);
  int*   sidx   = (int*)(ws + off);    off += (size_t)n * sizeof(int);
  int*   sel    = (int*)(ws + off);    off += (size_t)maxp * sizeof(int);
  int*   cnt    = (int*)(ws + off);    off += sizeof(int) * 4;
  int*   pos    = (int*)(ws + off);

  hipMemsetAsync(pos, 0, (size_t)n * sizeof(int), stream);

  int cpb = 1024;
  hipLaunchKernelGGL(k_rank_part, dim3((n + 255) / 256, (n + cpb - 1) / cpb),
                     dim3(256), 0, stream, preds, n, cpb, pos);
  hipLaunchKernelGGL(k_rank_scatter, dim3((n + 255) / 256), dim3(256), 0, stream,
                     preds, pos, n, sboxes, sidx);
  hipLaunchKernelGGL(k_mask, dim3(nw, nw), dim3(64), 0, stream,
                     sboxes, n, thr, T);
  hipLaunchKernelGGL(k_scan, dim3(1), dim3(320), 0, stream,
                     T, n, nw, maxp, sel, cnt);
  hipLaunchKernelGGL(k_emit, dim3((maxp + 255) / 256), dim3(256), 0, stream,
                     preds, sidx, sel, cnt, maxp, out);
}